// Round 14
// baseline (44.874 us; speedup 1.0000x reference)
//
#include <hip/hip_runtime.h>
#include <hip/hip_bf16.h>
#include <math.h>

#define N 2048
#define CIN 128
#define COUT 64
#define NEG 0.2f
#define JB 16
#define NJB (N / JB)       // 128 blocks

typedef __attribute__((ext_vector_type(8))) short short8;   // 8 bf16
typedef __attribute__((ext_vector_type(4))) float f32x4;

__device__ __forceinline__ ushort bf16u(float x) {
  __hip_bfloat16 b = __float2bfloat16(x);
  return *reinterpret_cast<ushort*>(&b);
}
__device__ __forceinline__ uint pack2(float lo, float hi) {
  return (uint)bf16u(lo) | ((uint)bf16u(hi) << 16);
}

// Single fused kernel: block bj owns j-rows [bj*16, bj*16+16). Its 16 waves
// split the K=32 i-panels round-robin; each wave REGENERATES the h-panel it
// needs (32 MFMA vs 4 attn MFMA — redundant gemm is ~1µs chip-wide) into a
// private LDS region laid out exactly like the verified hfrag format, then
// consumes it. W staged once as bf16 B-frags. No second kernel, no fences,
// no cross-block dependency.
__global__ __launch_bounds__(1024) void gat_fused(
    const float* __restrict__ data, const float* __restrict__ W,
    const float* __restrict__ att_src, const float* __restrict__ att_dst,
    const float* __restrict__ bias, float* __restrict__ out) {
  const int bj = NJB - 1 - (int)blockIdx.x;   // heavy blocks first
  const int tid = (int)threadIdx.x;
  const int wid = tid >> 6;
  const int lane = tid & 63;
  const int q = lane >> 4;
  const int n15 = lane & 15;
  const int j0 = bj * JB;
  const int jme = j0 + n15;
  const int nks = (bj + 2) >> 1;              // K=32 panels covering i <= j0+15

  // wbuf(16KB) + per-wave hbuf(16x4KB) in smem; rbuf(64KB) overlays them
  // in the epilogue phase (barrier-separated).
  __shared__ char smem[16384 + 16 * 4096];
  __shared__ float asbuf[16][32];
  __shared__ float adbuf[16];
  __shared__ float dbuf[16][16];
  ushort* wbuf = (ushort*)smem;
  ushort* hw = (ushort*)(smem + 16384 + wid * 4096);  // this wave's h panel
  float* rbuf = (float*)smem;                          // epilogue only

  // ---- stage W fragments: 1024 threads == 1024 frag slots (kc,ci,L) ----
  {
    const int kc = tid >> 8, L = tid & 63;
    const int ci = (tid >> 6) & 3;
    const int kr = kc * 32 + (L >> 4) * 8;
    const int cg = ci * 16 + (L & 15);
    ushort uw[8];
#pragma unroll
    for (int e = 0; e < 8; ++e) uw[e] = bf16u(W[(kr + e) * COUT + cg]);
    uint4 pw;
    pw.x = (uint)uw[0] | ((uint)uw[1] << 16);
    pw.y = (uint)uw[2] | ((uint)uw[3] << 16);
    pw.z = (uint)uw[4] | ((uint)uw[5] << 16);
    pw.w = (uint)uw[6] | ((uint)uw[7] << 16);
    *(uint4*)&wbuf[tid * 8] = pw;   // ((kc*4+ci)*64+L)*8 == tid*8
  }

  float srcv[4], dstv[4];
#pragma unroll
  for (int ci = 0; ci < 4; ++ci) {
    srcv[ci] = att_src[ci * 16 + n15];
    dstv[ci] = att_dst[ci * 16 + n15];
  }
  __syncthreads();  // W frags ready

  f32x4 pacc0 = {0.f, 0.f, 0.f, 0.f};
  f32x4 pacc1 = pacc0, pacc2 = pacc0, pacc3 = pacc0;
  float dsum = 0.f;
  float ad_me = 0.f;

  const int nt = (wid < nks) ? ((nks - 1 - wid) >> 4) + 1 : 0;
  const int w0 = (nks - 1) & 15;              // wave owning the last panel
  const int t_first = (wid == w0) ? ((nks - 1 - wid) >> 4) : 0;

  // generate h panel for i in [ks*32, ks*32+32) into hw (verified layout);
  // also a_s (and a_d for the j-panel when do_ad).
  auto gen_panel = [&](int ks, bool do_ad) {
    const int ibase = ks * 32;
    f32x4 acc[2][4];
#pragma unroll
    for (int mi = 0; mi < 2; ++mi)
#pragma unroll
      for (int ci = 0; ci < 4; ++ci) acc[mi][ci] = (f32x4){0.f, 0.f, 0.f, 0.f};

#pragma unroll
    for (int kc = 0; kc < 4; ++kc) {
      short8 af[2];
#pragma unroll
      for (int mi = 0; mi < 2; ++mi) {
        const int mrow = ibase + mi * 16 + n15;
        const int col = kc * 32 + q * 8;
        const float4 f0 = *(const float4*)&data[mrow * CIN + col];
        const float4 f1 = *(const float4*)&data[mrow * CIN + col + 4];
        uint4 pa;
        pa.x = pack2(f0.x, f0.y);
        pa.y = pack2(f0.z, f0.w);
        pa.z = pack2(f1.x, f1.y);
        pa.w = pack2(f1.z, f1.w);
        af[mi] = *(short8*)&pa;
      }
#pragma unroll
      for (int ci = 0; ci < 4; ++ci) {
        const short8 bw =
            *(const short8*)&wbuf[((kc * 4 + ci) * 64 + lane) * 8];
        acc[0][ci] = __builtin_amdgcn_mfma_f32_16x16x32_bf16(af[0], bw,
                                                             acc[0][ci], 0, 0, 0);
        acc[1][ci] = __builtin_amdgcn_mfma_f32_16x16x32_bf16(af[1], bw,
                                                             acc[1][ci], 0, 0, 0);
      }
    }

    // store h (C/D -> local hfrag layout: f=ci, lp, e = ibl&7) + a_s/a_d
    float ps[2][4] = {};
    float pd[2][4] = {};
#pragma unroll
    for (int mi = 0; mi < 2; ++mi) {
      const int ibl = mi * 16 + q * 4;
      const int lp = ((ibl >> 3) & 3) * 16 + n15;
#pragma unroll
      for (int ci = 0; ci < 4; ++ci) {
        uint2 hv;
        hv.x = pack2(acc[mi][ci][0], acc[mi][ci][1]);
        hv.y = pack2(acc[mi][ci][2], acc[mi][ci][3]);
        *(uint2*)&hw[(ci * 64 + lp) * 8 + (ibl & 7)] = hv;
#pragma unroll
        for (int r = 0; r < 4; ++r) {
          ps[mi][r] = fmaf(acc[mi][ci][r], srcv[ci], ps[mi][r]);
          if (do_ad) pd[mi][r] = fmaf(acc[mi][ci][r], dstv[ci], pd[mi][r]);
        }
      }
    }
#pragma unroll
    for (int off = 1; off < 16; off <<= 1)
#pragma unroll
      for (int mi = 0; mi < 2; ++mi)
#pragma unroll
        for (int r = 0; r < 4; ++r) ps[mi][r] += __shfl_xor(ps[mi][r], off);
    if (n15 == 0) {
#pragma unroll
      for (int mi = 0; mi < 2; ++mi)
#pragma unroll
        for (int r = 0; r < 4; ++r) asbuf[wid][mi * 16 + q * 4 + r] = ps[mi][r];
    }
    if (do_ad) {
#pragma unroll
      for (int off = 1; off < 16; off <<= 1)
#pragma unroll
        for (int mi = 0; mi < 2; ++mi)
#pragma unroll
          for (int r = 0; r < 4; ++r) pd[mi][r] += __shfl_xor(pd[mi][r], off);
      if (n15 == 0) {
        const int msel = bj & 1;  // j-rows sit in mi = bj&1 of the last panel
#pragma unroll
        for (int r = 0; r < 4; ++r)
          adbuf[q * 4 + r] = msel ? pd[1][r] : pd[0][r];
      }
    }
  };

  // consume the panel in hw: weights in-register, 4 attn MFMA
  auto consume = [&](int ks) {
    const int ibase = ks * 32;
    const float4 asa = *(const float4*)&asbuf[wid][q * 8];
    const float4 asb = *(const float4*)&asbuf[wid][q * 8 + 4];
    const float av[8] = {asa.x, asa.y, asa.z, asa.w,
                         asb.x, asb.y, asb.z, asb.w};
    short8 af;
#pragma unroll
    for (int e = 0; e < 8; ++e) {
      float x = av[e] + ad_me;
      x = fmaxf(x, NEG * x);                  // leaky_relu
      float wgt = __expf(x);                  // logits bounded: no max-shift
      if (ibase + q * 8 + e > jme) wgt = 0.f; // causal mask i <= j
      dsum += wgt;
      af[e] = (short)bf16u(wgt);
    }
    const short8 b0 = *(const short8*)&hw[(0 * 64 + lane) * 8];
    const short8 b1 = *(const short8*)&hw[(1 * 64 + lane) * 8];
    const short8 b2 = *(const short8*)&hw[(2 * 64 + lane) * 8];
    const short8 b3 = *(const short8*)&hw[(3 * 64 + lane) * 8];
    pacc0 = __builtin_amdgcn_mfma_f32_16x16x32_bf16(af, b0, pacc0, 0, 0, 0);
    pacc1 = __builtin_amdgcn_mfma_f32_16x16x32_bf16(af, b1, pacc1, 0, 0, 0);
    pacc2 = __builtin_amdgcn_mfma_f32_16x16x32_bf16(af, b2, pacc2, 0, 0, 0);
    pacc3 = __builtin_amdgcn_mfma_f32_16x16x32_bf16(af, b3, pacc3, 0, 0, 0);
  };

  // first panel (wave w0 does the a_d-bearing last panel first), then barrier
  if (nt > 0) gen_panel(wid + 16 * t_first, wid == w0);
  __syncthreads();  // a_d ready for everyone
  ad_me = adbuf[n15];
  if (nt > 0) consume(wid + 16 * t_first);

#pragma unroll 1
  for (int t = 0; t < nt; ++t) {
    if (t == t_first) continue;
    const int ks = wid + 16 * t;
    gen_panel(ks, false);
    consume(ks);
  }

  // den over the 4 k-chunks within the wave
  dsum += __shfl_xor(dsum, 16);
  dsum += __shfl_xor(dsum, 32);

  // ---- epilogue: rbuf overlays wbuf/hbuf -> barrier first ----
  __syncthreads();
#pragma unroll
  for (int r = 0; r < 4; ++r) {
    rbuf[((0 + r) * 16 + wid) * 64 + lane]  = pacc0[r];
    rbuf[((4 + r) * 16 + wid) * 64 + lane]  = pacc1[r];
    rbuf[((8 + r) * 16 + wid) * 64 + lane]  = pacc2[r];
    rbuf[((12 + r) * 16 + wid) * 64 + lane] = pacc3[r];
  }
  if (lane < 16) dbuf[wid][lane] = dsum;
  __syncthreads();

  {
    const int j = tid >> 6, c = tid & 63;
    const int qq = j >> 2, rr = j & 3, t16 = c >> 4, n = c & 15;
    float num = 0.f, den = 0.f;
#pragma unroll
    for (int ww = 0; ww < 16; ++ww) {
      num += rbuf[((t16 * 4 + rr) * 16 + ww) * 64 + qq * 16 + n];
      den += dbuf[ww][j];
    }
    const float v = num / den + bias[c];
    out[(size_t)(j0 + j) * COUT + c] = v > 0.f ? v : 0.f;
  }
}

extern "C" void kernel_launch(void* const* d_in, const int* in_sizes, int n_in,
                              void* d_out, int out_size, void* d_ws, size_t ws_size,
                              hipStream_t stream) {
  const float* data    = (const float*)d_in[0];  // [N, CIN]
  const float* W       = (const float*)d_in[1];  // [CIN, COUT]
  const float* att_src = (const float*)d_in[2];  // [COUT]
  const float* att_dst = (const float*)d_in[3];  // [COUT]
  const float* bias    = (const float*)d_in[4];  // [COUT]
  float* out = (float*)d_out;                    // [N, COUT]

  gat_fused<<<NJB, 1024, 0, stream>>>(data, W, att_src, att_dst, bias, out);
}

// Round 15
// 16.052 us; speedup vs baseline: 2.7955x; 2.7955x over previous
//
#include <hip/hip_runtime.h>
#include <hip/hip_bf16.h>
#include <math.h>

#define N 2048
#define CIN 128
#define COUT 64
#define NEG 0.2f
#define JB 16              // j-rows per attn block
#define NJB (N / JB)       // 128 attn blocks

typedef __attribute__((ext_vector_type(8))) short short8;   // 8 bf16
typedef __attribute__((ext_vector_type(4))) float f32x4;

__device__ __forceinline__ ushort bf16u(float x) {
  __hip_bfloat16 b = __float2bfloat16(x);
  return *reinterpret_cast<ushort*>(&b);
}
__device__ __forceinline__ uint pack2(float lo, float hi) {
  return (uint)bf16u(lo) | ((uint)bf16u(hi) << 16);
}

// Kernel 1: slim MFMA gemm (R13, proven). 128 blocks x 256 threads;
// block = 16-row tile; wave ci owns output cols [ci*16, ci*16+16).
__global__ __launch_bounds__(256) void gat_gemm_mfma(
    const float* __restrict__ data, const float* __restrict__ W,
    const float* __restrict__ att_src, const float* __restrict__ att_dst,
    ushort* __restrict__ hfrag, float* __restrict__ a_s,
    float* __restrict__ a_d) {
  const int tid = (int)threadIdx.x;
  const int ci = tid >> 6;            // wave = output col-tile
  const int lane = tid & 63;
  const int i0 = (int)blockIdx.x * 16;
  const int q = lane >> 4;            // k-subgroup / C-row group
  const int n15 = lane & 15;
  const int mrow = i0 + n15;          // A-frag row for this lane

  // A-frags: af[kc][e] = bf16(data[mrow][kc*32 + q*8 + e])
  short8 af[4];
#pragma unroll
  for (int kc = 0; kc < 4; ++kc) {
    const int col = kc * 32 + q * 8;
    const float4 f0 = *(const float4*)&data[mrow * CIN + col];
    const float4 f1 = *(const float4*)&data[mrow * CIN + col + 4];
    uint4 pa;
    pa.x = pack2(f0.x, f0.y);
    pa.y = pack2(f0.z, f0.w);
    pa.z = pack2(f1.x, f1.y);
    pa.w = pack2(f1.z, f1.w);
    af[kc] = *(short8*)&pa;
  }

  // B-frags + MFMA: bf[kc][e] = bf16(W[kc*32 + q*8 + e][ci*16 + n15])
  const int cg = ci * 16 + n15;
  f32x4 acc = {0.f, 0.f, 0.f, 0.f};
#pragma unroll
  for (int kc = 0; kc < 4; ++kc) {
    const int kr = kc * 32 + q * 8;
    ushort uw[8];
#pragma unroll
    for (int e = 0; e < 8; ++e) uw[e] = bf16u(W[(kr + e) * COUT + cg]);
    uint4 pw;
    pw.x = (uint)uw[0] | ((uint)uw[1] << 16);
    pw.y = (uint)uw[2] | ((uint)uw[3] << 16);
    pw.z = (uint)uw[4] | ((uint)uw[5] << 16);
    pw.w = (uint)uw[6] | ((uint)uw[7] << 16);
    acc = __builtin_amdgcn_mfma_f32_16x16x32_bf16(af[kc], *(short8*)&pw,
                                                  acc, 0, 0, 0);
  }

  // hfrag store: verified B-frag order (R8/R11/R12/R13 on-device)
  {
    const int ib = i0 + q * 4;
    const int f = (ib >> 5) * 4 + ci;
    const int lp = ((ib >> 3) & 3) * 16 + n15;
    uint2 hv;
    hv.x = pack2(acc[0], acc[1]);
    hv.y = pack2(acc[2], acc[3]);
    *(uint2*)&hfrag[((size_t)(f * 64 + lp) << 3) + (ib & 7)] = hv;
  }

  // a_s/a_d: per-wave 16-lane shuffle tree + tiny LDS cross-wave sum
  __shared__ float asp[4][16];
  __shared__ float adp[4][16];
  {
    const float sc = att_src[cg];
    const float dc = att_dst[cg];
    float ps[4], pd[4];
#pragma unroll
    for (int r = 0; r < 4; ++r) { ps[r] = acc[r] * sc; pd[r] = acc[r] * dc; }
#pragma unroll
    for (int off = 1; off < 16; off <<= 1) {
#pragma unroll
      for (int r = 0; r < 4; ++r) {
        ps[r] += __shfl_xor(ps[r], off);
        pd[r] += __shfl_xor(pd[r], off);
      }
    }
    if (n15 == 0) {
#pragma unroll
      for (int r = 0; r < 4; ++r) {
        asp[ci][q * 4 + r] = ps[r];
        adp[ci][q * 4 + r] = pd[r];
      }
    }
  }
  __syncthreads();
  if (tid < 16) {
    a_s[i0 + tid] = asp[0][tid] + asp[1][tid] + asp[2][tid] + asp[3][tid];
    a_d[i0 + tid] = adp[0][tid] + adp[1][tid] + adp[2][tid] + adp[3][tid];
  }
}

// Kernel 2: flash triangular MFMA attention, software-pipelined K-loop:
// step t+1's loads (a_s + 4 hfrag frags) are issued before step t's
// exp/pack/MFMA, hiding one load latency per iteration (T14 pattern).
__global__ __launch_bounds__(1024) void gat_attn_flash(
    const ushort* __restrict__ hfrag, const float* __restrict__ a_s,
    const float* __restrict__ a_d, const float* __restrict__ bias,
    float* __restrict__ out) {
  const int bj = NJB - 1 - (int)blockIdx.x;   // heavy blocks first
  const int tid = (int)threadIdx.x;
  const int wid = tid >> 6;                   // 0..15
  const int lane = tid & 63;
  const int j0 = bj * JB;
  const int jme = j0 + (lane & 15);
  const int kgrp = lane >> 4;
  const float ad_me = a_d[jme];
  const int nks = (bj + 2) >> 1;              // K=32 steps covering i<=j0+15

  f32x4 acc0 = {0.f, 0.f, 0.f, 0.f};
  f32x4 acc1 = acc0, acc2 = acc0, acc3 = acc0;
  float dsum = 0.f;
  const uint4* hf = (const uint4*)hfrag;

  // pipelined load/compute split
  float4 asa0, asb0;
  uint4 b00, b01, b02, b03;

  auto load_step = [&](int ks, float4& asa, float4& asb, uint4& b0, uint4& b1,
                       uint4& b2, uint4& b3) {
    const int ibase = ks * 32 + kgrp * 8;
    asa = *(const float4*)&a_s[ibase];
    asb = *(const float4*)&a_s[ibase + 4];
    const int fbase = (ks * 4) * 64 + lane;
    b0 = hf[fbase];
    b1 = hf[fbase + 64];
    b2 = hf[fbase + 128];
    b3 = hf[fbase + 192];
  };

  auto compute_step = [&](int ks, const float4& asa, const float4& asb,
                          const uint4& b0, const uint4& b1, const uint4& b2,
                          const uint4& b3) {
    const int ibase = ks * 32 + kgrp * 8;
    const float av[8] = {asa.x, asa.y, asa.z, asa.w,
                         asb.x, asb.y, asb.z, asb.w};
    short8 afw;
#pragma unroll
    for (int e = 0; e < 8; ++e) {
      float x = av[e] + ad_me;
      x = fmaxf(x, NEG * x);                  // leaky_relu
      float wgt = __expf(x);                  // no max-shift (logits bounded)
      if (ibase + e > jme) wgt = 0.f;         // causal mask i <= j
      dsum += wgt;
      afw[e] = (short)bf16u(wgt);
    }
    acc0 = __builtin_amdgcn_mfma_f32_16x16x32_bf16(afw, *(const short8*)&b0,
                                                   acc0, 0, 0, 0);
    acc1 = __builtin_amdgcn_mfma_f32_16x16x32_bf16(afw, *(const short8*)&b1,
                                                   acc1, 0, 0, 0);
    acc2 = __builtin_amdgcn_mfma_f32_16x16x32_bf16(afw, *(const short8*)&b2,
                                                   acc2, 0, 0, 0);
    acc3 = __builtin_amdgcn_mfma_f32_16x16x32_bf16(afw, *(const short8*)&b3,
                                                   acc3, 0, 0, 0);
  };

  int ks = wid;
  if (ks < nks) {
    load_step(ks, asa0, asb0, b00, b01, b02, b03);
#pragma unroll 1
    while (ks + 16 < nks) {
      float4 asa1, asb1;
      uint4 b10, b11, b12, b13;
      load_step(ks + 16, asa1, asb1, b10, b11, b12, b13);   // prefetch next
      compute_step(ks, asa0, asb0, b00, b01, b02, b03);     // compute current
      asa0 = asa1; asb0 = asb1;
      b00 = b10; b01 = b11; b02 = b12; b03 = b13;
      ks += 16;
    }
    compute_step(ks, asa0, asb0, b00, b01, b02, b03);
  }

  // den over the 4 k-chunks within the wave
  dsum += __shfl_xor(dsum, 16);
  dsum += __shfl_xor(dsum, 32);

  __shared__ float rbuf[16][16][64];   // [t16*4+r][wid][lane] (64KB)
  __shared__ float dbuf[16][16];       // [wid][j]
#pragma unroll
  for (int r = 0; r < 4; ++r) {
    rbuf[0 + r][wid][lane]  = acc0[r];
    rbuf[4 + r][wid][lane]  = acc1[r];
    rbuf[8 + r][wid][lane]  = acc2[r];
    rbuf[12 + r][wid][lane] = acc3[r];
  }
  if (lane < 16) dbuf[wid][lane] = dsum;
  __syncthreads();

  // epilogue: thread handles output elem (j = tid>>6, c = tid&63)
  {
    const int j = tid >> 6, c = tid & 63;
    const int qq = j >> 2, rr = j & 3, t16 = c >> 4, n = c & 15;
    float num = 0.f, den = 0.f;
#pragma unroll
    for (int ww = 0; ww < 16; ++ww) {
      num += rbuf[t16 * 4 + rr][ww][qq * 16 + n];
      den += dbuf[ww][j];
    }
    const float v = num / den + bias[c];
    out[(size_t)(j0 + j) * COUT + c] = v > 0.f ? v : 0.f;
  }
}

extern "C" void kernel_launch(void* const* d_in, const int* in_sizes, int n_in,
                              void* d_out, int out_size, void* d_ws, size_t ws_size,
                              hipStream_t stream) {
  const float* data    = (const float*)d_in[0];  // [N, CIN]
  const float* W       = (const float*)d_in[1];  // [CIN, COUT]
  const float* att_src = (const float*)d_in[2];  // [COUT]
  const float* att_dst = (const float*)d_in[3];  // [COUT]
  const float* bias    = (const float*)d_in[4];  // [COUT]
  float* out = (float*)d_out;                    // [N, COUT]

  ushort* hfrag = (ushort*)d_ws;                 // N*COUT bf16 (256KB)
  float* a_s  = (float*)d_ws + 65536;            // N
  float* a_d  = a_s + N;                         // N

  gat_gemm_mfma<<<N / 16, 256, 0, stream>>>(data, W, att_src, att_dst,
                                            hfrag, a_s, a_d);
  gat_attn_flash<<<NJB, 1024, 0, stream>>>(hfrag, a_s, a_d, bias, out);
}

// Round 16
// 15.450 us; speedup vs baseline: 2.9045x; 1.0390x over previous
//
#include <hip/hip_runtime.h>
#include <hip/hip_bf16.h>
#include <math.h>

#define N 2048
#define CIN 128
#define COUT 64
#define NEG 0.2f
#define JB 16              // j-rows per attn block
#define NJB (N / JB)       // 128 attn blocks

typedef __attribute__((ext_vector_type(8))) short short8;   // 8 bf16
typedef __attribute__((ext_vector_type(4))) float f32x4;

__device__ __forceinline__ ushort bf16u(float x) {
  __hip_bfloat16 b = __float2bfloat16(x);
  return *reinterpret_cast<ushort*>(&b);
}
__device__ __forceinline__ uint pack2(float lo, float hi) {
  return (uint)bf16u(lo) | ((uint)bf16u(hi) << 16);
}

// Kernel 1: slim MFMA gemm (R13, measured best). 128 blocks x 256 threads;
// block = 16-row tile; wave ci owns output cols [ci*16, ci*16+16).
// All 4 waves share the tile's A-frags -> load/pack A global->reg (no LDS,
// no barrier on the MFMA path).
__global__ __launch_bounds__(256) void gat_gemm_mfma(
    const float* __restrict__ data, const float* __restrict__ W,
    const float* __restrict__ att_src, const float* __restrict__ att_dst,
    ushort* __restrict__ hfrag, float* __restrict__ a_s,
    float* __restrict__ a_d) {
  const int tid = (int)threadIdx.x;
  const int ci = tid >> 6;            // wave = output col-tile
  const int lane = tid & 63;
  const int i0 = (int)blockIdx.x * 16;
  const int q = lane >> 4;            // k-subgroup / C-row group
  const int n15 = lane & 15;
  const int mrow = i0 + n15;          // A-frag row for this lane

  // A-frags: af[kc][e] = bf16(data[mrow][kc*32 + q*8 + e])
  short8 af[4];
#pragma unroll
  for (int kc = 0; kc < 4; ++kc) {
    const int col = kc * 32 + q * 8;
    const float4 f0 = *(const float4*)&data[mrow * CIN + col];
    const float4 f1 = *(const float4*)&data[mrow * CIN + col + 4];
    uint4 pa;
    pa.x = pack2(f0.x, f0.y);
    pa.y = pack2(f0.z, f0.w);
    pa.z = pack2(f1.x, f1.y);
    pa.w = pack2(f1.z, f1.w);
    af[kc] = *(short8*)&pa;
  }

  // B-frags + MFMA: bf[kc][e] = bf16(W[kc*32 + q*8 + e][ci*16 + n15])
  const int cg = ci * 16 + n15;
  f32x4 acc = {0.f, 0.f, 0.f, 0.f};
#pragma unroll
  for (int kc = 0; kc < 4; ++kc) {
    const int kr = kc * 32 + q * 8;
    ushort uw[8];
#pragma unroll
    for (int e = 0; e < 8; ++e) uw[e] = bf16u(W[(kr + e) * COUT + cg]);
    uint4 pw;
    pw.x = (uint)uw[0] | ((uint)uw[1] << 16);
    pw.y = (uint)uw[2] | ((uint)uw[3] << 16);
    pw.z = (uint)uw[4] | ((uint)uw[5] << 16);
    pw.w = (uint)uw[6] | ((uint)uw[7] << 16);
    acc = __builtin_amdgcn_mfma_f32_16x16x32_bf16(af[kc], *(short8*)&pw,
                                                  acc, 0, 0, 0);
  }

  // hfrag store: verified B-frag order (R8/R11/R12/R13 on-device)
  {
    const int ib = i0 + q * 4;
    const int f = (ib >> 5) * 4 + ci;
    const int lp = ((ib >> 3) & 3) * 16 + n15;
    uint2 hv;
    hv.x = pack2(acc[0], acc[1]);
    hv.y = pack2(acc[2], acc[3]);
    *(uint2*)&hfrag[((size_t)(f * 64 + lp) << 3) + (ib & 7)] = hv;
  }

  // a_s/a_d: per-wave 16-lane shuffle tree + tiny LDS cross-wave sum
  __shared__ float asp[4][16];
  __shared__ float adp[4][16];
  {
    const float sc = att_src[cg];
    const float dc = att_dst[cg];
    float ps[4], pd[4];
#pragma unroll
    for (int r = 0; r < 4; ++r) { ps[r] = acc[r] * sc; pd[r] = acc[r] * dc; }
#pragma unroll
    for (int off = 1; off < 16; off <<= 1) {
#pragma unroll
      for (int r = 0; r < 4; ++r) {
        ps[r] += __shfl_xor(ps[r], off);
        pd[r] += __shfl_xor(pd[r], off);
      }
    }
    if (n15 == 0) {
#pragma unroll
      for (int r = 0; r < 4; ++r) {
        asp[ci][q * 4 + r] = ps[r];
        adp[ci][q * 4 + r] = pd[r];
      }
    }
  }
  __syncthreads();
  if (tid < 16) {
    a_s[i0 + tid] = asp[0][tid] + asp[1][tid] + asp[2][tid] + asp[3][tid];
    a_d[i0 + tid] = adp[0][tid] + adp[1][tid] + adp[2][tid] + adp[3][tid];
  }
}

// Kernel 2: flash triangular MFMA attention (R12/R13 structure, measured
// best; no manual pipelining — R15 showed it regresses). 128 blocks x 1024
// threads; block bj owns 16 j's; 16 waves split K=32 i-steps round-robin.
__global__ __launch_bounds__(1024) void gat_attn_flash(
    const ushort* __restrict__ hfrag, const float* __restrict__ a_s,
    const float* __restrict__ a_d, const float* __restrict__ bias,
    float* __restrict__ out) {
  const int bj = NJB - 1 - (int)blockIdx.x;   // heavy blocks first
  const int tid = (int)threadIdx.x;
  const int wid = tid >> 6;                   // 0..15
  const int lane = tid & 63;
  const int j0 = bj * JB;
  const int jme = j0 + (lane & 15);
  const int kgrp = lane >> 4;
  const float ad_me = a_d[jme];
  const int nks = (bj + 2) >> 1;              // K=32 steps covering i<=j0+15

  f32x4 acc0 = {0.f, 0.f, 0.f, 0.f};
  f32x4 acc1 = acc0, acc2 = acc0, acc3 = acc0;
  float dsum = 0.f;
  const uint4* hf = (const uint4*)hfrag;

  for (int ks = wid; ks < nks; ks += 16) {
    const int ibase = ks * 32 + kgrp * 8;
    const float4 asa = *(const float4*)&a_s[ibase];
    const float4 asb = *(const float4*)&a_s[ibase + 4];
    const float av[8] = {asa.x, asa.y, asa.z, asa.w,
                         asb.x, asb.y, asb.z, asb.w};
    short8 afw;
#pragma unroll
    for (int e = 0; e < 8; ++e) {
      float x = av[e] + ad_me;
      x = fmaxf(x, NEG * x);                  // leaky_relu
      float wgt = __expf(x);                  // no max-shift (logits bounded)
      if (ibase + e > jme) wgt = 0.f;         // causal mask i <= j
      dsum += wgt;
      afw[e] = (short)bf16u(wgt);
    }
    const int fbase = (ks * 4) * 64 + lane;
    const uint4 b0 = hf[fbase];
    const uint4 b1 = hf[fbase + 64];
    const uint4 b2 = hf[fbase + 128];
    const uint4 b3 = hf[fbase + 192];
    acc0 = __builtin_amdgcn_mfma_f32_16x16x32_bf16(afw, *(const short8*)&b0,
                                                   acc0, 0, 0, 0);
    acc1 = __builtin_amdgcn_mfma_f32_16x16x32_bf16(afw, *(const short8*)&b1,
                                                   acc1, 0, 0, 0);
    acc2 = __builtin_amdgcn_mfma_f32_16x16x32_bf16(afw, *(const short8*)&b2,
                                                   acc2, 0, 0, 0);
    acc3 = __builtin_amdgcn_mfma_f32_16x16x32_bf16(afw, *(const short8*)&b3,
                                                   acc3, 0, 0, 0);
  }

  // den over the 4 k-chunks within the wave
  dsum += __shfl_xor(dsum, 16);
  dsum += __shfl_xor(dsum, 32);

  __shared__ float rbuf[16][16][64];   // [t16*4+r][wid][lane] (64KB)
  __shared__ float dbuf[16][16];       // [wid][j]
#pragma unroll
  for (int r = 0; r < 4; ++r) {
    rbuf[0 + r][wid][lane]  = acc0[r];
    rbuf[4 + r][wid][lane]  = acc1[r];
    rbuf[8 + r][wid][lane]  = acc2[r];
    rbuf[12 + r][wid][lane] = acc3[r];
  }
  if (lane < 16) dbuf[wid][lane] = dsum;
  __syncthreads();

  // epilogue: thread handles output elem (j = tid>>6, c = tid&63)
  {
    const int j = tid >> 6, c = tid & 63;
    const int qq = j >> 2, rr = j & 3, t16 = c >> 4, n = c & 15;
    float num = 0.f, den = 0.f;
#pragma unroll
    for (int ww = 0; ww < 16; ++ww) {
      num += rbuf[t16 * 4 + rr][ww][qq * 16 + n];
      den += dbuf[ww][j];
    }
    const float v = num / den + bias[c];
    out[(size_t)(j0 + j) * COUT + c] = v > 0.f ? v : 0.f;
  }
}

extern "C" void kernel_launch(void* const* d_in, const int* in_sizes, int n_in,
                              void* d_out, int out_size, void* d_ws, size_t ws_size,
                              hipStream_t stream) {
  const float* data    = (const float*)d_in[0];  // [N, CIN]
  const float* W       = (const float*)d_in[1];  // [CIN, COUT]
  const float* att_src = (const float*)d_in[2];  // [COUT]
  const float* att_dst = (const float*)d_in[3];  // [COUT]
  const float* bias    = (const float*)d_in[4];  // [COUT]
  float* out = (float*)d_out;                    // [N, COUT]

  ushort* hfrag = (ushort*)d_ws;                 // N*COUT bf16 (256KB)
  float* a_s  = (float*)d_ws + 65536;            // N
  float* a_d  = a_s + N;                         // N

  gat_gemm_mfma<<<N / 16, 256, 0, stream>>>(data, W, att_src, att_dst,
                                            hfrag, a_s, a_d);
  gat_attn_flash<<<NJB, 1024, 0, stream>>>(hfrag, a_s, a_d, bias, out);
}

// Round 17
// 14.273 us; speedup vs baseline: 3.1440x; 1.0825x over previous
//
#include <hip/hip_runtime.h>
#include <hip/hip_bf16.h>
#include <math.h>

#define N 2048
#define CIN 128
#define COUT 64
#define NEG 0.2f
#define JB 16              // j-rows per attn block
#define NJB (N / JB)       // 128 j-blocks; x2 channel halves = 256 blocks

typedef __attribute__((ext_vector_type(8))) short short8;   // 8 bf16
typedef __attribute__((ext_vector_type(4))) float f32x4;

__device__ __forceinline__ ushort bf16u(float x) {
  __hip_bfloat16 b = __float2bfloat16(x);
  return *reinterpret_cast<ushort*>(&b);
}
__device__ __forceinline__ uint pack2(float lo, float hi) {
  return (uint)bf16u(lo) | ((uint)bf16u(hi) << 16);
}

// Kernel 1: slim MFMA gemm (R13, measured best — unchanged).
__global__ __launch_bounds__(256) void gat_gemm_mfma(
    const float* __restrict__ data, const float* __restrict__ W,
    const float* __restrict__ att_src, const float* __restrict__ att_dst,
    ushort* __restrict__ hfrag, float* __restrict__ a_s,
    float* __restrict__ a_d) {
  const int tid = (int)threadIdx.x;
  const int ci = tid >> 6;            // wave = output col-tile
  const int lane = tid & 63;
  const int i0 = (int)blockIdx.x * 16;
  const int q = lane >> 4;            // k-subgroup / C-row group
  const int n15 = lane & 15;
  const int mrow = i0 + n15;          // A-frag row for this lane

  short8 af[4];
#pragma unroll
  for (int kc = 0; kc < 4; ++kc) {
    const int col = kc * 32 + q * 8;
    const float4 f0 = *(const float4*)&data[mrow * CIN + col];
    const float4 f1 = *(const float4*)&data[mrow * CIN + col + 4];
    uint4 pa;
    pa.x = pack2(f0.x, f0.y);
    pa.y = pack2(f0.z, f0.w);
    pa.z = pack2(f1.x, f1.y);
    pa.w = pack2(f1.z, f1.w);
    af[kc] = *(short8*)&pa;
  }

  const int cg = ci * 16 + n15;
  f32x4 acc = {0.f, 0.f, 0.f, 0.f};
#pragma unroll
  for (int kc = 0; kc < 4; ++kc) {
    const int kr = kc * 32 + q * 8;
    ushort uw[8];
#pragma unroll
    for (int e = 0; e < 8; ++e) uw[e] = bf16u(W[(kr + e) * COUT + cg]);
    uint4 pw;
    pw.x = (uint)uw[0] | ((uint)uw[1] << 16);
    pw.y = (uint)uw[2] | ((uint)uw[3] << 16);
    pw.z = (uint)uw[4] | ((uint)uw[5] << 16);
    pw.w = (uint)uw[6] | ((uint)uw[7] << 16);
    acc = __builtin_amdgcn_mfma_f32_16x16x32_bf16(af[kc], *(short8*)&pw,
                                                  acc, 0, 0, 0);
  }

  // hfrag store: verified B-frag order (R8..R16 on-device)
  {
    const int ib = i0 + q * 4;
    const int f = (ib >> 5) * 4 + ci;
    const int lp = ((ib >> 3) & 3) * 16 + n15;
    uint2 hv;
    hv.x = pack2(acc[0], acc[1]);
    hv.y = pack2(acc[2], acc[3]);
    *(uint2*)&hfrag[((size_t)(f * 64 + lp) << 3) + (ib & 7)] = hv;
  }

  __shared__ float asp[4][16];
  __shared__ float adp[4][16];
  {
    const float sc = att_src[cg];
    const float dc = att_dst[cg];
    float ps[4], pd[4];
#pragma unroll
    for (int r = 0; r < 4; ++r) { ps[r] = acc[r] * sc; pd[r] = acc[r] * dc; }
#pragma unroll
    for (int off = 1; off < 16; off <<= 1) {
#pragma unroll
      for (int r = 0; r < 4; ++r) {
        ps[r] += __shfl_xor(ps[r], off);
        pd[r] += __shfl_xor(pd[r], off);
      }
    }
    if (n15 == 0) {
#pragma unroll
      for (int r = 0; r < 4; ++r) {
        asp[ci][q * 4 + r] = ps[r];
        adp[ci][q * 4 + r] = pd[r];
      }
    }
  }
  __syncthreads();
  if (tid < 16) {
    a_s[i0 + tid] = asp[0][tid] + asp[1][tid] + asp[2][tid] + asp[3][tid];
    a_d[i0 + tid] = adp[0][tid] + adp[1][tid] + adp[2][tid] + adp[3][tid];
  }
}

// Kernel 2: flash triangular MFMA attention, split by output-channel half.
// 256 blocks x 1024 threads: block (bj, chalf) computes channels
// [chalf*32, chalf*32+32) of j-rows [bj*16, +16). Per K-step: 2 hfrag
// loads + 8 exp (redundant across halves, VALU-cheap) + 2 MFMA.
// All 256 CUs get a block; per-wave serial work halves vs R16.
__global__ __launch_bounds__(1024) void gat_attn_flash(
    const ushort* __restrict__ hfrag, const float* __restrict__ a_s,
    const float* __restrict__ a_d, const float* __restrict__ bias,
    float* __restrict__ out) {
  const int b = (int)blockIdx.x;
  const int bj = NJB - 1 - (b >> 1);          // heavy j-blocks first
  const int chalf = b & 1;                    // channel half 0/1
  const int tid = (int)threadIdx.x;
  const int wid = tid >> 6;                   // 0..15
  const int lane = tid & 63;
  const int j0 = bj * JB;
  const int jme = j0 + (lane & 15);
  const int kgrp = lane >> 4;
  const float ad_me = a_d[jme];
  const int nks = (bj + 2) >> 1;              // K=32 steps covering i<=j0+15

  f32x4 acc0 = {0.f, 0.f, 0.f, 0.f};
  f32x4 acc1 = acc0;
  float dsum = 0.f;
  const uint4* hf = (const uint4*)hfrag;

  for (int ks = wid; ks < nks; ks += 16) {
    const int ibase = ks * 32 + kgrp * 8;
    const float4 asa = *(const float4*)&a_s[ibase];
    const float4 asb = *(const float4*)&a_s[ibase + 4];
    const float av[8] = {asa.x, asa.y, asa.z, asa.w,
                         asb.x, asb.y, asb.z, asb.w};
    short8 afw;
#pragma unroll
    for (int e = 0; e < 8; ++e) {
      float x = av[e] + ad_me;
      x = fmaxf(x, NEG * x);                  // leaky_relu
      float wgt = __expf(x);                  // no max-shift (logits bounded)
      if (ibase + e > jme) wgt = 0.f;         // causal mask i <= j
      dsum += wgt;
      afw[e] = (short)bf16u(wgt);
    }
    const int fbase = (ks * 4 + chalf * 2) * 64 + lane;
    const uint4 b0 = hf[fbase];
    const uint4 b1 = hf[fbase + 64];
    acc0 = __builtin_amdgcn_mfma_f32_16x16x32_bf16(afw, *(const short8*)&b0,
                                                   acc0, 0, 0, 0);
    acc1 = __builtin_amdgcn_mfma_f32_16x16x32_bf16(afw, *(const short8*)&b1,
                                                   acc1, 0, 0, 0);
  }

  // den over the 4 k-chunks within the wave (identical in both halves)
  dsum += __shfl_xor(dsum, 16);
  dsum += __shfl_xor(dsum, 32);

  __shared__ float rbuf[8][16][64];    // [t16*4+r][wid][lane] (32KB)
  __shared__ float dbuf[16][16];       // [wid][j]
#pragma unroll
  for (int r = 0; r < 4; ++r) {
    rbuf[r][wid][lane]     = acc0[r];
    rbuf[4 + r][wid][lane] = acc1[r];
  }
  if (lane < 16) dbuf[wid][lane] = dsum;
  __syncthreads();

  // epilogue: 512 outputs (16j x 32c); thread tid<512 handles one
  if (tid < 512) {
    const int j = tid >> 5, cl = tid & 31;
    const int qq = j >> 2, rr = j & 3, t16 = cl >> 4, n = cl & 15;
    float num = 0.f, den = 0.f;
#pragma unroll
    for (int ww = 0; ww < 16; ++ww) {
      num += rbuf[t16 * 4 + rr][ww][qq * 16 + n];
      den += dbuf[ww][j];
    }
    const int cg = chalf * 32 + cl;
    const float v = num / den + bias[cg];
    out[(size_t)(j0 + j) * COUT + cg] = v > 0.f ? v : 0.f;
  }
}

extern "C" void kernel_launch(void* const* d_in, const int* in_sizes, int n_in,
                              void* d_out, int out_size, void* d_ws, size_t ws_size,
                              hipStream_t stream) {
  const float* data    = (const float*)d_in[0];  // [N, CIN]
  const float* W       = (const float*)d_in[1];  // [CIN, COUT]
  const float* att_src = (const float*)d_in[2];  // [COUT]
  const float* att_dst = (const float*)d_in[3];  // [COUT]
  const float* bias    = (const float*)d_in[4];  // [COUT]
  float* out = (float*)d_out;                    // [N, COUT]

  ushort* hfrag = (ushort*)d_ws;                 // N*COUT bf16 (256KB)
  float* a_s  = (float*)d_ws + 65536;            // N
  float* a_d  = a_s + N;                         // N

  gat_gemm_mfma<<<N / 16, 256, 0, stream>>>(data, W, att_src, att_dst,
                                            hfrag, a_s, a_d);
  gat_attn_flash<<<NJB * 2, 1024, 0, stream>>>(hfrag, a_s, a_d, bias, out);
}